// Round 2
// baseline (288.804 us; speedup 1.0000x reference)
//
#include <hip/hip_runtime.h>
#include <hip/hip_fp16.h>
#include <hip/hip_cooperative_groups.h>

namespace cg = cooperative_groups;

#define TAU 0.07f
#define MARGIN 0.2f
#define NSPEC 64
#define BB 8192
#define DD 256

// ---------------- ws layout (bytes) ----------------
//   0      float scalars[8] [0]=triSum [1]=infoSum [2]=n_valid [3]=n_valid_i [4]=done  (zero P0)
//   64     int   cnt2[64]    scatter cursors                                           (zero P0)
//   320    int   counts[64]                                                            (write P1)
//   576    int   offsets[64]                                                           (write P1)
//   832    int   hist8[8*64] per-block histograms                                      (write P0)
//   3072   float T[256]                                                                (zero P0, atomic P2)
//   4096   float lseRow[8192]                                                          (zero P0, atomic P2)
//   36864  float lseCol[8192]                                                          (zero P0, atomic P2)
//   68608  float Ts[64*256]                                                            (zero P0, atomic P2)
//   134144 int   memberList[8192]                                                      (write P1)
#define WS_SCALARS   0
#define WS_CNT2      64
#define WS_COUNTS    320
#define WS_OFFSETS   576
#define WS_HIST8     832
#define WS_T         3072
#define WS_LSEROW    4096
#define WS_LSECOL    36864
#define WS_TS        68608
#define WS_MEMBER    134144

typedef _Float16 half8 __attribute__((ext_vector_type(8)));
typedef float float4v __attribute__((ext_vector_type(4)));
typedef unsigned int uint4v __attribute__((ext_vector_type(4)));

__device__ __forceinline__ uint4v pack8(float4 a, float4 b) {
  half8 h;
  h[0] = (_Float16)a.x; h[1] = (_Float16)a.y; h[2] = (_Float16)a.z; h[3] = (_Float16)a.w;
  h[4] = (_Float16)b.x; h[5] = (_Float16)b.y; h[6] = (_Float16)b.z; h[7] = (_Float16)b.w;
  return __builtin_bit_cast(uint4v, h);
}

__device__ __forceinline__ float dot4(float4 a, float4 b) {
  return a.x * b.x + a.y * b.y + a.z * b.z + a.w * b.w;
}

// One cooperative kernel, 512 blocks x 256 threads, 3 grid syncs.
__global__ void __launch_bounds__(256, 2)
fused_all(const float* __restrict__ sp, const float* __restrict__ tx,
          const int* __restrict__ ids, char* __restrict__ ws, float* __restrict__ out) {
  float* scalars = (float*)(ws + WS_SCALARS);
  int* cnt2 = (int*)(ws + WS_CNT2);
  int* counts = (int*)(ws + WS_COUNTS);
  int* offsets = (int*)(ws + WS_OFFSETS);
  int* hist8 = (int*)(ws + WS_HIST8);
  float* T = (float*)(ws + WS_T);
  float* lseRow = (float*)(ws + WS_LSEROW);
  float* lseCol = (float*)(ws + WS_LSECOL);
  float* Ts = (float*)(ws + WS_TS);
  int* memberList = (int*)(ws + WS_MEMBER);

  cg::grid_group grid = cg::this_grid();
  int bid = blockIdx.x, tid = threadIdx.x;

  __shared__ union {
    int lhist[NSPEC];                           // P0
    struct { int cnts[NSPEC]; int offs[NSPEC]; } p1;  // P1
    uint4v lds5[1536];                          // P2 (24 KB)
    float red[8];                               // P3
  } sm;

  // ---------------- P0: histogram (blocks 0..7) | zero accumulators (blocks 8+) ----
  if (bid < 8) {
    if (tid < NSPEC) sm.lhist[tid] = 0;
    __syncthreads();
    #pragma unroll
    for (int r = 0; r < 4; ++r) {
      int i = bid * 1024 + r * 256 + tid;
      atomicAdd(&sm.lhist[ids[i]], 1);
    }
    __syncthreads();
    if (tid < NSPEC) hist8[bid * NSPEC + tid] = sm.lhist[tid];
  } else {
    int z = (bid - 8) * 256 + tid;
    float4v z4 = {0.f, 0.f, 0.f, 0.f};
    if (z < 8192) *(float4v*)(ws + WS_T + z * 16) = z4;       // [3072, 134144)
    else if (z < 8212) *(float4v*)(ws + (z - 8192) * 16) = z4; // [0, 320)
  }
  grid.sync();

  // ---------------- P1: scan + scatter (blocks 0..31), stats (block 0) -------------
  if (bid < 32) {
    if (tid < NSPEC) {
      int c = 0;
      #pragma unroll
      for (int b = 0; b < 8; ++b) c += hist8[b * NSPEC + tid];
      sm.p1.cnts[tid] = c;
    }
    __syncthreads();
    if (tid == 0) {
      int o = 0;
      for (int s2 = 0; s2 < NSPEC; ++s2) { sm.p1.offs[s2] = o; o += sm.p1.cnts[s2]; }
    }
    __syncthreads();
    int i = bid * 256 + tid;                    // each element exactly once
    int s = ids[i];
    int pos = sm.p1.offs[s] + atomicAdd(&cnt2[s], 1);
    memberList[pos] = i;
    if (bid == 0) {
      if (tid < NSPEC) { counts[tid] = sm.p1.cnts[tid]; offsets[tid] = sm.p1.offs[tid]; }
      if (tid == 0) {
        float nv = 0.f, nvi = 0.f;
        for (int s2 = 0; s2 < NSPEC; ++s2) {
          int c = sm.p1.cnts[s2];
          if (c >= 2) { nv += 1.f; if (c <= BB - 1) nvi += (float)c; }
        }
        scalars[2] = nv; scalars[3] = nvi;
      }
    }
  }
  grid.sync();

  // ---------------- P2: k2 slices (Ts,T) + k5 MFMA LSE tiles -----------------------
  {
    int s = bid & 63;
    int m = counts[s];
    int g0 = offsets[s];
    int r = bid >> 6;                           // 0..7

    // k2 slice: per-species partial sums -> Ts[s][d] and global T[d]
    {
      int k0 = (m * r) >> 3, k1e = (m * (r + 1)) >> 3;
      if (k0 < k1e) {
        int d = tid;
        float acc = 0.f;
        for (int k = k0; k < k1e; ++k) acc += tx[memberList[g0 + k] * DD + d];
        atomicAdd(&Ts[s * DD + d], acc);
        atomicAdd(&T[d], acc);                  // sum over ALL slices == sum of all tx rows
      }
    }

    // k5 tiles: 64x128 masked sum-of-exp via MFMA f16, K=256 in 4 chunks
    int lane = tid & 63, wv = tid >> 6;
    int quad = lane >> 4, cl = lane & 15;
    int rt0 = (bid >> 6) & 3, ct0 = bid >> 8;   // strides 4, 2 (512 blocks = 64x4x2)

    for (int rt = rt0; rt * 64 < m; rt += 4) {
      for (int ct = ct0; ct * 128 < m; ct += 2) {
        float4v acc[8];
        #pragma unroll
        for (int cf = 0; cf < 8; ++cf) acc[cf] = (float4v){0.f, 0.f, 0.f, 0.f};

        for (int kc = 0; kc < 4; ++kc) {
          __syncthreads();
          #pragma unroll
          for (int p = 0; p < 6; ++p) {
            int u = p * 256 + tid;
            int isB = u >= 512;
            int v = isB ? (u - 512) : u;
            int row = v >> 3;
            int sub = v & 7;
            int ksl = sub >> 2, q = sub & 3;
            int d0 = kc * 64 + ksl * 32 + q * 8;
            int idx = isB ? (ct * 128 + row) : (rt * 64 + row);
            uint4v val = (uint4v){0u, 0u, 0u, 0u};
            if (idx < m) {
              const float* src = (isB ? tx : sp) + memberList[g0 + idx] * DD + d0;
              float4 f0 = *reinterpret_cast<const float4*>(src);
              float4 f1 = *reinterpret_cast<const float4*>(src + 4);
              val = pack8(f0, f1);
            }
            int dst = isB ? (512 + (ksl * 128 + row) * 4 + q)
                          : ((ksl * 64 + row) * 4 + q);
            sm.lds5[dst] = val;
          }
          __syncthreads();
          #pragma unroll
          for (int ksl = 0; ksl < 2; ++ksl) {
            half8 a = __builtin_bit_cast(half8, sm.lds5[(ksl * 64 + wv * 16 + cl) * 4 + quad]);
            #pragma unroll
            for (int cf = 0; cf < 8; ++cf) {
              half8 b = __builtin_bit_cast(half8, sm.lds5[512 + (ksl * 128 + cf * 16 + cl) * 4 + quad]);
              acc[cf] = __builtin_amdgcn_mfma_f32_16x16x32_f16(a, b, acc[cf], 0, 0, 0);
            }
          }
        }

        // epilogue: masked exp, row/col sums
        int riBase = rt * 64 + wv * 16 + quad * 4;
        float rowAcc[4] = {0.f, 0.f, 0.f, 0.f};
        #pragma unroll
        for (int cf = 0; cf < 8; ++cf) {
          int ci = ct * 128 + cf * 16 + cl;
          bool cv = ci < m;
          float colAcc = 0.f;
          #pragma unroll
          for (int reg = 0; reg < 4; ++reg) {
            bool rv = (riBase + reg) < m;
            float e = (rv && cv) ? __expf(acc[cf][reg] * (1.f / TAU)) : 0.f;
            rowAcc[reg] += e;
            colAcc += e;
          }
          colAcc += __shfl_xor(colAcc, 16);
          colAcc += __shfl_xor(colAcc, 32);
          if (quad == 0 && cv) atomicAdd(&lseCol[g0 + ci], colAcc);
        }
        #pragma unroll
        for (int reg = 0; reg < 4; ++reg) {
          float v = rowAcc[reg];
          v += __shfl_xor(v, 1);
          v += __shfl_xor(v, 2);
          v += __shfl_xor(v, 4);
          v += __shfl_xor(v, 8);
          if (cl == 0 && (riBase + reg) < m) atomicAdd(&lseRow[g0 + riBase + reg], v);
        }
      }
    }
  }
  grid.sync();

  // ---------------- P3: dots + CE + triplet, block reduce, done-counter finalize ---
  {
    int wv = tid >> 6, lane = tid & 63;
    int wg = bid * 4 + wv;                      // 2048 waves, 4 rows each
    float termAcc = 0.f, triAcc = 0.f;
    #pragma unroll
    for (int j = 0; j < 4; ++j) {
      int g = wg + j * 2048;
      int i = memberList[g];
      int s = ids[i];
      int m = counts[s];
      float4 a = *reinterpret_cast<const float4*>(sp + i * DD + lane * 4);
      float4 b = *reinterpret_cast<const float4*>(tx + i * DD + lane * 4);
      float4 c = *reinterpret_cast<const float4*>(Ts + s * DD + lane * 4);
      float4 tv = *reinterpret_cast<const float4*>(T + lane * 4);
      float dDiag = dot4(a, b);
      float dTs = dot4(a, c);
      float dT = dot4(a, tv);
      #pragma unroll
      for (int o = 1; o < 64; o <<= 1) {
        dDiag += __shfl_xor(dDiag, o);
        dTs   += __shfl_xor(dTs, o);
        dT    += __shfl_xor(dT, o);
      }
      if (lane == 0 && m >= 2) {
        termAcc += (__logf(lseRow[g]) + __logf(lseCol[g]) - 2.f * dDiag * (1.f / TAU)) /
                   (2.f * (float)m);
        if (m <= BB - 1) {
          float posMean = (dTs - dDiag) / fmaxf((float)(m - 1), 1.f);
          float negMean = (dT - dTs) / fmaxf((float)(BB - m), 1.f);
          triAcc += fmaxf(negMean - posMean + MARGIN, 0.f);
        }
      }
    }
    if (lane == 0) { sm.red[wv] = termAcc; sm.red[4 + wv] = triAcc; }
    __syncthreads();
    if (tid == 0) {
      float infoS = sm.red[0] + sm.red[1] + sm.red[2] + sm.red[3];
      float triS = sm.red[4] + sm.red[5] + sm.red[6] + sm.red[7];
      atomicAdd(&scalars[1], infoS);
      atomicAdd(&scalars[0], triS);
      __threadfence();
      unsigned prev = atomicAdd((unsigned*)&scalars[4], 1u);
      if (prev == (unsigned)(gridDim.x - 1)) {   // last block: finalize
        float fi = atomicAdd(&scalars[1], 0.f);  // coherent device-scope reads
        float ft = atomicAdd(&scalars[0], 0.f);
        float nv = atomicAdd(&scalars[2], 0.f);
        float nvi = atomicAdd(&scalars[3], 0.f);
        out[0] = fi / fmaxf(nv, 1.f) + ft / fmaxf(nvi, 1.f);
      }
    }
  }
}

extern "C" void kernel_launch(void* const* d_in, const int* in_sizes, int n_in,
                              void* d_out, int out_size, void* d_ws, size_t ws_size,
                              hipStream_t stream) {
  const float* sp = (const float*)d_in[0];
  const float* tx = (const float*)d_in[1];
  const int* ids = (const int*)d_in[2];
  float* out = (float*)d_out;
  char* ws = (char*)d_ws;

  void* args[] = {(void*)&sp, (void*)&tx, (void*)&ids, (void*)&ws, (void*)&out};
  hipLaunchCooperativeKernel((void*)fused_all, dim3(512), dim3(256), args, 0, stream);
}

// Round 3
// 121.972 us; speedup vs baseline: 2.3678x; 2.3678x over previous
//
#include <hip/hip_runtime.h>
#include <hip/hip_fp16.h>

#define TAU 0.07f
#define MARGIN 0.2f
#define NSPEC 64
#define BB 8192
#define DD 256

// ---------------- ws layout (bytes) ----------------
// zeroed by k1 each call:
//   0      float scalars[8]  [0]=triSum [1]=infoSum [2]=n_valid [3]=n_valid_i [4]=done
//   1024   float lseRow[8192]   [1024,  33792)
//   33792  float lseCol[8192]   [33792, 66560)
//   66560  float Ts[64*256]     [66560, 132096)
//   132096 float T[256]         [132096,133120)
// unzeroed (fully written by k1):
//   64     int   counts[64]
//   320    int   offsets[64]
//   133120 int   memberList[8192]
#define WS_SCALARS   0
#define WS_COUNTS    64
#define WS_OFFSETS   320
#define WS_LSEROW    1024
#define WS_LSECOL    33792
#define WS_TS        66560
#define WS_T         132096
#define WS_MEMBER    133120
#define ZERO_F4      8256   // float4 count covering [1024, 133120)

typedef _Float16 half8 __attribute__((ext_vector_type(8)));
typedef float float4v __attribute__((ext_vector_type(4)));
typedef unsigned int uint4v __attribute__((ext_vector_type(4)));

__device__ __forceinline__ uint4v pack8(float4 a, float4 b) {
  half8 h;
  h[0] = (_Float16)a.x; h[1] = (_Float16)a.y; h[2] = (_Float16)a.z; h[3] = (_Float16)a.w;
  h[4] = (_Float16)b.x; h[5] = (_Float16)b.y; h[6] = (_Float16)b.z; h[7] = (_Float16)b.w;
  return __builtin_bit_cast(uint4v, h);
}

__device__ __forceinline__ float dot4(float4 a, float4 b) {
  return a.x * b.x + a.y * b.y + a.z * b.z + a.w * b.w;
}

// ---- k1: ws zeroing + counts + scan + scatter + valid-counts, single block 1024 thr ----
__global__ void k1_all(const int* __restrict__ ids, int* counts_g, int* offsets_g,
                       int* memberList, float* scalars, char* ws) {
  __shared__ int cnt[NSPEC];
  __shared__ int off[NSPEC];
  int tid = threadIdx.x;
  // zero the accumulated region (replaces hipMemsetAsync dispatch)
  float4v z4 = {0.f, 0.f, 0.f, 0.f};
  float4v* zb = (float4v*)(ws + WS_LSEROW);
  for (int u = tid; u < ZERO_F4; u += 1024) zb[u] = z4;
  if (tid < 16) ((unsigned*)ws)[tid] = 0u;  // scalars region
  if (tid < NSPEC) cnt[tid] = 0;
  __syncthreads();
  int myS[8], myP[8];
  #pragma unroll
  for (int r = 0; r < 8; ++r) {
    int i = r * 1024 + tid;
    int s = ids[i];
    myS[r] = s;
    myP[r] = atomicAdd(&cnt[s], 1);
  }
  __syncthreads();
  if (tid < NSPEC) {  // exactly wave 0
    int o = 0;
    for (int t = 0; t < NSPEC; ++t) o += (t < tid) ? cnt[t] : 0;
    off[tid] = o;
    offsets_g[tid] = o;
    int c = cnt[tid];
    counts_g[tid] = c;
    unsigned long long bv = __ballot(c >= 2);
    float nvi = (c >= 2 && c <= BB - 1) ? (float)c : 0.f;
    for (int o2 = 1; o2 < 64; o2 <<= 1) nvi += __shfl_xor(nvi, o2);
    if (tid == 0) {
      scalars[2] = (float)__popcll(bv);
      scalars[3] = nvi;
    }
  }
  __syncthreads();
  #pragma unroll
  for (int r = 0; r < 8; ++r) {
    int i = r * 1024 + tid;
    memberList[off[myS[r]] + myP[r]] = i;
  }
}

// ---- kmid: blocks 0..511 = k5 MFMA-LSE tiles; blocks 512..1023 = k2 Ts/T slices ----
__global__ void kmid(const float* __restrict__ sp, const float* __restrict__ tx,
                     const int* __restrict__ counts, const int* __restrict__ offsets,
                     const int* __restrict__ memberList,
                     float* Ts, float* T, float* lseRow, float* lseCol) {
  __shared__ uint4v lds5[1536];  // k5 role only (24 KB)
  int bid = blockIdx.x;
  int tid = threadIdx.x;

  if (bid >= 512) {
    // ---- k2 role: per-species text sums Ts[s][d] + global T[d], 8 row-slices ----
    int v = bid - 512;
    int s = v & 63, r = v >> 6;
    int m = counts[s], g0 = offsets[s];
    int k0 = (m * r) >> 3, k1e = (m * (r + 1)) >> 3;
    if (k0 >= k1e) return;
    int d = tid;
    float acc = 0.f;
    for (int k = k0; k < k1e; ++k) acc += tx[memberList[g0 + k] * DD + d];
    atomicAdd(&Ts[s * DD + d], acc);
    atomicAdd(&T[d], acc);  // sum over ALL slices == sum over all tx rows
    return;
  }

  // ---- k5 role: 64x128 masked sum-of-exp via MFMA f16, K=256 in 4 chunks ----
  int s = bid & 63;
  int m = counts[s];
  int g0 = offsets[s];
  int lane = tid & 63, wv = tid >> 6;
  int quad = lane >> 4, cl = lane & 15;
  int rt0 = (bid >> 6) & 3, ct0 = (bid >> 8) & 1;  // strides 4, 2

  for (int rt = rt0; rt * 64 < m; rt += 4) {
    for (int ct = ct0; ct * 128 < m; ct += 2) {
      float4v acc[8];
      #pragma unroll
      for (int cf = 0; cf < 8; ++cf) acc[cf] = (float4v){0.f, 0.f, 0.f, 0.f};

      for (int kc = 0; kc < 4; ++kc) {
        __syncthreads();
        // stage 1536 units, 6 per thread
        #pragma unroll
        for (int p = 0; p < 6; ++p) {
          int u = p * 256 + tid;
          int isB = u >= 512;
          int v = isB ? (u - 512) : u;
          int row = v >> 3;            // A: 0..63 ; B: 0..127
          int sub = v & 7;
          int ksl = sub >> 2, q = sub & 3;
          int d0 = kc * 64 + ksl * 32 + q * 8;
          int idx = isB ? (ct * 128 + row) : (rt * 64 + row);
          uint4v val = (uint4v){0u, 0u, 0u, 0u};
          if (idx < m) {
            const float* src = (isB ? tx : sp) + memberList[g0 + idx] * DD + d0;
            float4 f0 = *reinterpret_cast<const float4*>(src);
            float4 f1 = *reinterpret_cast<const float4*>(src + 4);
            val = pack8(f0, f1);
          }
          int dst = isB ? (512 + (ksl * 128 + row) * 4 + q)
                        : ((ksl * 64 + row) * 4 + q);
          lds5[dst] = val;
        }
        __syncthreads();
        #pragma unroll
        for (int ksl = 0; ksl < 2; ++ksl) {
          half8 a = __builtin_bit_cast(half8, lds5[(ksl * 64 + wv * 16 + cl) * 4 + quad]);
          #pragma unroll
          for (int cf = 0; cf < 8; ++cf) {
            half8 b = __builtin_bit_cast(half8, lds5[512 + (ksl * 128 + cf * 16 + cl) * 4 + quad]);
            acc[cf] = __builtin_amdgcn_mfma_f32_16x16x32_f16(a, b, acc[cf], 0, 0, 0);
          }
        }
      }

      // epilogue: masked exp, row/col sums
      int riBase = rt * 64 + wv * 16 + quad * 4;  // + reg
      float rowAcc[4] = {0.f, 0.f, 0.f, 0.f};
      #pragma unroll
      for (int cf = 0; cf < 8; ++cf) {
        int ci = ct * 128 + cf * 16 + cl;
        bool cv = ci < m;
        float colAcc = 0.f;
        #pragma unroll
        for (int reg = 0; reg < 4; ++reg) {
          bool rv = (riBase + reg) < m;
          float e = (rv && cv) ? __expf(acc[cf][reg] * (1.f / TAU)) : 0.f;
          rowAcc[reg] += e;
          colAcc += e;
        }
        colAcc += __shfl_xor(colAcc, 16);
        colAcc += __shfl_xor(colAcc, 32);
        if (quad == 0 && cv) atomicAdd(&lseCol[g0 + ci], colAcc);
      }
      #pragma unroll
      for (int reg = 0; reg < 4; ++reg) {
        float v = rowAcc[reg];
        v += __shfl_xor(v, 1);
        v += __shfl_xor(v, 2);
        v += __shfl_xor(v, 4);
        v += __shfl_xor(v, 8);
        if (cl == 0 && (riBase + reg) < m) atomicAdd(&lseRow[g0 + riBase + reg], v);
      }
    }
  }
}

// ---- kend: fused k4+k6+k7: one wave per g does the 3 exact f32 dots + CE + triplet,
//      block reduce, one atomic pair per block, last block writes the final output ----
__global__ void kend(const float* __restrict__ sp, const float* __restrict__ tx,
                     const int* __restrict__ ids, const int* __restrict__ counts,
                     const int* __restrict__ memberList,
                     const float* __restrict__ Ts, const float* __restrict__ T,
                     const float* __restrict__ lseRow, const float* __restrict__ lseCol,
                     float* scalars, float* out) {
  __shared__ float red[32];  // [0..15]=info per wave, [16..31]=tri per wave
  int tid = threadIdx.x;
  int gt = blockIdx.x * 1024 + tid;
  int g = gt >> 6, lane = gt & 63;
  int i = memberList[g];
  int s = ids[i];
  int m = counts[s];
  float4 a = *reinterpret_cast<const float4*>(sp + i * DD + lane * 4);
  float4 b = *reinterpret_cast<const float4*>(tx + i * DD + lane * 4);
  float4 c = *reinterpret_cast<const float4*>(Ts + s * DD + lane * 4);
  float4 tv = *reinterpret_cast<const float4*>(T + lane * 4);
  float dDiag = dot4(a, b);
  float dTs   = dot4(a, c);
  float dT    = dot4(a, tv);
  #pragma unroll
  for (int o = 1; o < 64; o <<= 1) {
    dDiag += __shfl_xor(dDiag, o);
    dTs   += __shfl_xor(dTs, o);
    dT    += __shfl_xor(dT, o);
  }
  if (lane == 0) {
    float term = 0.f, tri = 0.f;
    if (m >= 2) {
      term = (__logf(lseRow[g]) + __logf(lseCol[g]) - 2.f * dDiag * (1.f / TAU)) /
             (2.f * (float)m);
      float posMean = (dTs - dDiag) / fmaxf((float)(m - 1), 1.f);
      float negMean = (dT - dTs) / fmaxf((float)(BB - m), 1.f);
      if (m <= BB - 1) tri = fmaxf(negMean - posMean + MARGIN, 0.f);
    }
    int wv = tid >> 6;
    red[wv] = term;
    red[16 + wv] = tri;
  }
  __syncthreads();
  if (tid == 0) {
    float infoS = 0.f, triS = 0.f;
    #pragma unroll
    for (int w = 0; w < 16; ++w) { infoS += red[w]; triS += red[16 + w]; }
    atomicAdd(&scalars[1], infoS);
    atomicAdd(&scalars[0], triS);
    __threadfence();
    unsigned prev = atomicAdd((unsigned*)&scalars[4], 1u);
    if (prev == (unsigned)(gridDim.x - 1)) {   // last block: finalize
      float fi = atomicAdd(&scalars[1], 0.f);  // coherent device-scope reads
      float ft = atomicAdd(&scalars[0], 0.f);
      float nv = scalars[2];   // plain k1 outputs: visible since kernel boundary
      float nvi = scalars[3];
      out[0] = fi / fmaxf(nv, 1.f) + ft / fmaxf(nvi, 1.f);
    }
  }
}

extern "C" void kernel_launch(void* const* d_in, const int* in_sizes, int n_in,
                              void* d_out, int out_size, void* d_ws, size_t ws_size,
                              hipStream_t stream) {
  const float* sp = (const float*)d_in[0];
  const float* tx = (const float*)d_in[1];
  const int* ids = (const int*)d_in[2];
  float* out = (float*)d_out;

  char* ws = (char*)d_ws;
  float* scalars = (float*)(ws + WS_SCALARS);
  int* counts = (int*)(ws + WS_COUNTS);
  int* offsets = (int*)(ws + WS_OFFSETS);
  float* lseRow = (float*)(ws + WS_LSEROW);
  float* lseCol = (float*)(ws + WS_LSECOL);
  float* Ts = (float*)(ws + WS_TS);
  float* T = (float*)(ws + WS_T);
  int* memberList = (int*)(ws + WS_MEMBER);

  k1_all<<<1, 1024, 0, stream>>>(ids, counts, offsets, memberList, scalars, ws);
  kmid<<<1024, 256, 0, stream>>>(sp, tx, counts, offsets, memberList, Ts, T,
                                 lseRow, lseCol);
  kend<<<512, 1024, 0, stream>>>(sp, tx, ids, counts, memberList, Ts, T,
                                 lseRow, lseCol, scalars, out);
}

// Round 4
// 111.968 us; speedup vs baseline: 2.5793x; 1.0893x over previous
//
#include <hip/hip_runtime.h>
#include <hip/hip_fp16.h>

#define TAU 0.07f
#define MARGIN 0.2f
#define NSPEC 64
#define BB 8192
#define DD 256

// ---------------- ws layout (bytes) ----------------
// zeroed by hipMemsetAsync [0, 133120):
//   0      float scalars[8] [0]=triSum [1]=infoSum [2]=n_valid [3]=n_valid_i [4]=done
//   1024   float lseRow[8192]
//   33792  float lseCol[8192]
//   66560  float Ts[64*256]
//   132096 float T[256]
// unzeroed (fully written by k1):
//   133120 int memberList[8192]
//   165888 int counts[64]
//   166144 int offsets[64]
#define WS_SCALARS   0
#define WS_LSEROW    1024
#define WS_LSECOL    33792
#define WS_TS        66560
#define WS_T         132096
#define WS_ZERO_BYTES 133120
#define WS_MEMBER    133120
#define WS_COUNTS    165888
#define WS_OFFSETS   166144

typedef _Float16 half8 __attribute__((ext_vector_type(8)));
typedef float float4v __attribute__((ext_vector_type(4)));
typedef unsigned int uint4v __attribute__((ext_vector_type(4)));

__device__ __forceinline__ uint4v pack8(float4 a, float4 b) {
  half8 h;
  h[0] = (_Float16)a.x; h[1] = (_Float16)a.y; h[2] = (_Float16)a.z; h[3] = (_Float16)a.w;
  h[4] = (_Float16)b.x; h[5] = (_Float16)b.y; h[6] = (_Float16)b.z; h[7] = (_Float16)b.w;
  return __builtin_bit_cast(uint4v, h);
}

__device__ __forceinline__ float dot4(float4 a, float4 b) {
  return a.x * b.x + a.y * b.y + a.z * b.z + a.w * b.w;
}

// ---- k1: counts + scan + scatter + valid-counts, single block 1024 thr (round-0 form) ----
__global__ void k1_all(const int* __restrict__ ids, int* counts_g, int* offsets_g,
                       int* memberList, float* scalars) {
  __shared__ int cnt[NSPEC];
  __shared__ int off[NSPEC];
  int tid = threadIdx.x;
  if (tid < NSPEC) cnt[tid] = 0;
  __syncthreads();
  int myS[8], myP[8];
  #pragma unroll
  for (int r = 0; r < 8; ++r) {
    int i = r * 1024 + tid;
    int s = ids[i];
    myS[r] = s;
    myP[r] = atomicAdd(&cnt[s], 1);
  }
  __syncthreads();
  if (tid < NSPEC) {  // exactly wave 0
    int o = 0;
    for (int t = 0; t < NSPEC; ++t) o += (t < tid) ? cnt[t] : 0;
    off[tid] = o;
    offsets_g[tid] = o;
    int c = cnt[tid];
    counts_g[tid] = c;
    unsigned long long bv = __ballot(c >= 2);
    float nvi = (c >= 2 && c <= BB - 1) ? (float)c : 0.f;
    for (int o2 = 1; o2 < 64; o2 <<= 1) nvi += __shfl_xor(nvi, o2);
    if (tid == 0) {
      scalars[2] = (float)__popcll(bv);
      scalars[3] = nvi;
    }
  }
  __syncthreads();
  #pragma unroll
  for (int r = 0; r < 8; ++r) {
    int i = r * 1024 + tid;
    memberList[off[myS[r]] + myP[r]] = i;
  }
}

// ---- kmid: bid<512 = k5 MFMA-LSE (latency-optimized); 512..1023 = k2 Ts slices;
//            1024..1055 = T direct from tx ----
__global__ void kmid(const float* __restrict__ sp, const float* __restrict__ tx,
                     const int* __restrict__ counts, const int* __restrict__ offsets,
                     const int* __restrict__ memberList,
                     float* Ts, float* T, float* lseRow, float* lseCol) {
  __shared__ uint4v frag[1536];  // 24 KB (k5 role)
  __shared__ int idx[192];       // tile row indices: A rows [0,64), B rows [64,192)
  int bid = blockIdx.x;
  int tid = threadIdx.x;

  if (bid >= 1024) {
    // ---- T role: 32 blocks, each sums 256 rows of tx directly; 32 adds/address ----
    int r0 = (bid - 1024) * 256;
    int d = tid;
    float acc = 0.f;
    #pragma unroll 8
    for (int rr = 0; rr < 256; ++rr) acc += tx[(r0 + rr) * DD + d];
    atomicAdd(&T[d], acc);
    return;
  }
  if (bid >= 512) {
    // ---- k2 role: per-species text sums Ts[s][d], batched-gather pipeline ----
    int v2 = bid - 512;
    int s = v2 & 63, r = v2 >> 6;
    int m = counts[s], g0 = offsets[s];
    int k0 = (m * r) >> 3, k1e = (m * (r + 1)) >> 3;
    if (k0 >= k1e) return;
    int d = tid;
    float acc = 0.f;
    int k = k0;
    for (; k + 4 <= k1e; k += 4) {
      int i0 = memberList[g0 + k];
      int i1 = memberList[g0 + k + 1];
      int i2 = memberList[g0 + k + 2];
      int i3 = memberList[g0 + k + 3];
      float a0 = tx[i0 * DD + d];
      float a1 = tx[i1 * DD + d];
      float a2 = tx[i2 * DD + d];
      float a3 = tx[i3 * DD + d];
      acc += a0 + a1 + a2 + a3;
    }
    for (; k < k1e; ++k) acc += tx[memberList[g0 + k] * DD + d];
    atomicAdd(&Ts[s * DD + d], acc);
    return;
  }

  // ---- k5 role: 64x128 masked sum-of-exp via MFMA f16, K=256 in 4 chunks ----
  int s = bid & 63;
  int m = counts[s];
  int g0 = offsets[s];
  int lane = tid & 63, wv = tid >> 6;
  int quad = lane >> 4, cl = lane & 15;
  int rt0 = (bid >> 6) & 3, ct0 = (bid >> 8) & 1;  // strides 4, 2

  for (int rt = rt0; rt * 64 < m; rt += 4) {
    for (int ct = ct0; ct * 128 < m; ct += 2) {
      // tile prologue: hoist member indices to LDS ONCE per tile (not per kc)
      __syncthreads();  // previous tile fully done with idx/frag
      if (tid < 192) {
        int base = (tid < 64) ? (rt * 64 + tid) : (ct * 128 + (tid - 64));
        idx[tid] = (base < m) ? memberList[g0 + base] : -1;
      }
      __syncthreads();

      // per-unit setup (kc-independent): 6 units/thread
      const float* srcB[6];
      bool val[6];
      int dst[6];
      float4 r0[6], r1[6];
      #pragma unroll
      for (int p = 0; p < 6; ++p) {
        int u = p * 256 + tid;
        int isB = u >= 512;
        int v = isB ? (u - 512) : u;
        int row = v >> 3, sub = v & 7;
        int ksl = sub >> 2, q = sub & 3;
        int ridx = idx[isB ? (64 + row) : row];
        val[p] = ridx >= 0;
        srcB[p] = (isB ? tx : sp) + (val[p] ? ridx : 0) * DD + ksl * 32 + q * 8;
        dst[p] = isB ? (512 + (ksl * 128 + row) * 4 + q)
                     : ((ksl * 64 + row) * 4 + q);
      }
      // preload kc=0 into registers
      #pragma unroll
      for (int p = 0; p < 6; ++p) {
        r0[p] = *reinterpret_cast<const float4*>(srcB[p]);
        r1[p] = *reinterpret_cast<const float4*>(srcB[p] + 4);
      }

      float4v acc[8];
      #pragma unroll
      for (int cf = 0; cf < 8; ++cf) acc[cf] = (float4v){0.f, 0.f, 0.f, 0.f};

      for (int kc = 0; kc < 4; ++kc) {
        __syncthreads();  // previous MFMA done reading LDS
        uint4v z4 = (uint4v){0u, 0u, 0u, 0u};
        #pragma unroll
        for (int p = 0; p < 6; ++p)
          frag[dst[p]] = val[p] ? pack8(r0[p], r1[p]) : z4;
        __syncthreads();
        // issue next chunk's loads BEFORE MFMA: latency hides under matrix phase
        if (kc < 3) {
          #pragma unroll
          for (int p = 0; p < 6; ++p) {
            r0[p] = *reinterpret_cast<const float4*>(srcB[p] + (kc + 1) * 64);
            r1[p] = *reinterpret_cast<const float4*>(srcB[p] + (kc + 1) * 64 + 4);
          }
        }
        #pragma unroll
        for (int ksl = 0; ksl < 2; ++ksl) {
          half8 a = __builtin_bit_cast(half8, frag[(ksl * 64 + wv * 16 + cl) * 4 + quad]);
          #pragma unroll
          for (int cf = 0; cf < 8; ++cf) {
            half8 b = __builtin_bit_cast(half8, frag[512 + (ksl * 128 + cf * 16 + cl) * 4 + quad]);
            acc[cf] = __builtin_amdgcn_mfma_f32_16x16x32_f16(a, b, acc[cf], 0, 0, 0);
          }
        }
      }

      // epilogue: masked exp, row/col sums (unchanged, proven)
      int riBase = rt * 64 + wv * 16 + quad * 4;
      float rowAcc[4] = {0.f, 0.f, 0.f, 0.f};
      #pragma unroll
      for (int cf = 0; cf < 8; ++cf) {
        int ci = ct * 128 + cf * 16 + cl;
        bool cv = ci < m;
        float colAcc = 0.f;
        #pragma unroll
        for (int reg = 0; reg < 4; ++reg) {
          bool rv = (riBase + reg) < m;
          float e = (rv && cv) ? __expf(acc[cf][reg] * (1.f / TAU)) : 0.f;
          rowAcc[reg] += e;
          colAcc += e;
        }
        colAcc += __shfl_xor(colAcc, 16);
        colAcc += __shfl_xor(colAcc, 32);
        if (quad == 0 && cv) atomicAdd(&lseCol[g0 + ci], colAcc);
      }
      #pragma unroll
      for (int reg = 0; reg < 4; ++reg) {
        float v = rowAcc[reg];
        v += __shfl_xor(v, 1);
        v += __shfl_xor(v, 2);
        v += __shfl_xor(v, 4);
        v += __shfl_xor(v, 8);
        if (cl == 0 && (riBase + reg) < m) atomicAdd(&lseRow[g0 + riBase + reg], v);
      }
    }
  }
}

// ---- kend: fused dots + CE + triplet + done-counter finalize (verbatim from R3, passed) ----
__global__ void kend(const float* __restrict__ sp, const float* __restrict__ tx,
                     const int* __restrict__ ids, const int* __restrict__ counts,
                     const int* __restrict__ memberList,
                     const float* __restrict__ Ts, const float* __restrict__ T,
                     const float* __restrict__ lseRow, const float* __restrict__ lseCol,
                     float* scalars, float* out) {
  __shared__ float red[32];
  int tid = threadIdx.x;
  int gt = blockIdx.x * 1024 + tid;
  int g = gt >> 6, lane = gt & 63;
  int i = memberList[g];
  int s = ids[i];
  int m = counts[s];
  float4 a = *reinterpret_cast<const float4*>(sp + i * DD + lane * 4);
  float4 b = *reinterpret_cast<const float4*>(tx + i * DD + lane * 4);
  float4 c = *reinterpret_cast<const float4*>(Ts + s * DD + lane * 4);
  float4 tv = *reinterpret_cast<const float4*>(T + lane * 4);
  float dDiag = dot4(a, b);
  float dTs   = dot4(a, c);
  float dT    = dot4(a, tv);
  #pragma unroll
  for (int o = 1; o < 64; o <<= 1) {
    dDiag += __shfl_xor(dDiag, o);
    dTs   += __shfl_xor(dTs, o);
    dT    += __shfl_xor(dT, o);
  }
  if (lane == 0) {
    float term = 0.f, tri = 0.f;
    if (m >= 2) {
      term = (__logf(lseRow[g]) + __logf(lseCol[g]) - 2.f * dDiag * (1.f / TAU)) /
             (2.f * (float)m);
      float posMean = (dTs - dDiag) / fmaxf((float)(m - 1), 1.f);
      float negMean = (dT - dTs) / fmaxf((float)(BB - m), 1.f);
      if (m <= BB - 1) tri = fmaxf(negMean - posMean + MARGIN, 0.f);
    }
    int wv = tid >> 6;
    red[wv] = term;
    red[16 + wv] = tri;
  }
  __syncthreads();
  if (tid == 0) {
    float infoS = 0.f, triS = 0.f;
    #pragma unroll
    for (int w = 0; w < 16; ++w) { infoS += red[w]; triS += red[16 + w]; }
    atomicAdd(&scalars[1], infoS);
    atomicAdd(&scalars[0], triS);
    __threadfence();
    unsigned prev = atomicAdd((unsigned*)&scalars[4], 1u);
    if (prev == (unsigned)(gridDim.x - 1)) {
      float fi = atomicAdd(&scalars[1], 0.f);
      float ft = atomicAdd(&scalars[0], 0.f);
      float nv = scalars[2];
      float nvi = scalars[3];
      out[0] = fi / fmaxf(nv, 1.f) + ft / fmaxf(nvi, 1.f);
    }
  }
}

extern "C" void kernel_launch(void* const* d_in, const int* in_sizes, int n_in,
                              void* d_out, int out_size, void* d_ws, size_t ws_size,
                              hipStream_t stream) {
  const float* sp = (const float*)d_in[0];
  const float* tx = (const float*)d_in[1];
  const int* ids = (const int*)d_in[2];
  float* out = (float*)d_out;

  char* ws = (char*)d_ws;
  float* scalars = (float*)(ws + WS_SCALARS);
  float* lseRow = (float*)(ws + WS_LSEROW);
  float* lseCol = (float*)(ws + WS_LSECOL);
  float* Ts = (float*)(ws + WS_TS);
  float* T = (float*)(ws + WS_T);
  int* memberList = (int*)(ws + WS_MEMBER);
  int* counts = (int*)(ws + WS_COUNTS);
  int* offsets = (int*)(ws + WS_OFFSETS);

  hipMemsetAsync(d_ws, 0, WS_ZERO_BYTES, stream);
  k1_all<<<1, 1024, 0, stream>>>(ids, counts, offsets, memberList, scalars);
  kmid<<<1056, 256, 0, stream>>>(sp, tx, counts, offsets, memberList, Ts, T,
                                 lseRow, lseCol);
  kend<<<512, 1024, 0, stream>>>(sp, tx, ids, counts, memberList, Ts, T,
                                 lseRow, lseCol, scalars, out);
}

// Round 5
// 109.084 us; speedup vs baseline: 2.6475x; 1.0264x over previous
//
#include <hip/hip_runtime.h>
#include <hip/hip_fp16.h>

#define TAU 0.07f
#define MARGIN 0.2f
#define NSPEC 64
#define BB 8192
#define DD 256

// ---------------- ws layout (bytes) ----------------
//   0      float scalars[8] [0]=triSum [1]=infoSum [2]=n_valid [3]=n_valid_i [4]=done
//                                        (zeroed by kA block 0, then [2],[3] written)
//   64     int   counts[64]              (kA block 0)
//   320    int   offsets[64]             (kA block 0)
//   1024   float lseRow[8192]  32 KB     (zeroed by kA blocks 1-32; atomic kB)
//   33792  float lseCol[8192]  32 KB     (zeroed by kA blocks 1-32; atomic kB)
//   66560  float Ts[64][256]   64 KB     (zeroed by kA blocks 1-32; atomic kB)
//   132096 float T[256]        1 KB      (plain-written by kB block 1024)
//   133120 int   memberList[8192] 32 KB  (kA block 0)
//   165888 float Tpart[128][256] 128 KB  (plain-written by kA blocks 1-32)
#define WS_SCALARS   0
#define WS_COUNTS    64
#define WS_OFFSETS   320
#define WS_LSEROW    1024
#define WS_LSECOL    33792
#define WS_TS        66560
#define WS_T         132096
#define WS_MEMBER    133120
#define WS_TPART     165888

typedef _Float16 half8 __attribute__((ext_vector_type(8)));
typedef float float4v __attribute__((ext_vector_type(4)));
typedef unsigned int uint4v __attribute__((ext_vector_type(4)));

__device__ __forceinline__ uint4v pack8(float4 a, float4 b) {
  half8 h;
  h[0] = (_Float16)a.x; h[1] = (_Float16)a.y; h[2] = (_Float16)a.z; h[3] = (_Float16)a.w;
  h[4] = (_Float16)b.x; h[5] = (_Float16)b.y; h[6] = (_Float16)b.z; h[7] = (_Float16)b.w;
  return __builtin_bit_cast(uint4v, h);
}

__device__ __forceinline__ float dot4(float4 a, float4 b) {
  return a.x * b.x + a.y * b.y + a.z * b.z + a.w * b.w;
}

// ---- kA: block 0 = histogram/scan/scatter (+scalars zero);
//          blocks 1..32 = zero 128KB accumulators (disjoint) + Tpart partial text sums ----
__global__ void kA(const int* __restrict__ ids, const float* __restrict__ tx,
                   char* __restrict__ ws) {
  int bid = blockIdx.x, tid = threadIdx.x;
  if (bid == 0) {
    int* counts_g = (int*)(ws + WS_COUNTS);
    int* offsets_g = (int*)(ws + WS_OFFSETS);
    int* memberList = (int*)(ws + WS_MEMBER);
    float* scalars = (float*)(ws + WS_SCALARS);
    __shared__ int cnt[NSPEC];
    __shared__ int off[NSPEC];
    if (tid < 8) ((unsigned*)scalars)[tid] = 0u;
    if (tid < NSPEC) cnt[tid] = 0;
    __syncthreads();
    int myS[8], myP[8];
    #pragma unroll
    for (int r = 0; r < 8; ++r) {
      int i = r * 1024 + tid;
      int s = ids[i];
      myS[r] = s;
      myP[r] = atomicAdd(&cnt[s], 1);
    }
    __syncthreads();
    if (tid < NSPEC) {  // exactly wave 0
      int o = 0;
      for (int t = 0; t < NSPEC; ++t) o += (t < tid) ? cnt[t] : 0;
      off[tid] = o;
      offsets_g[tid] = o;
      int c = cnt[tid];
      counts_g[tid] = c;
      unsigned long long bv = __ballot(c >= 2);
      float nvi = (c >= 2 && c <= BB - 1) ? (float)c : 0.f;
      for (int o2 = 1; o2 < 64; o2 <<= 1) nvi += __shfl_xor(nvi, o2);
      if (tid == 0) {
        scalars[2] = (float)__popcll(bv);
        scalars[3] = nvi;
      }
    }
    __syncthreads();
    #pragma unroll
    for (int r = 0; r < 8; ++r) {
      int i = r * 1024 + tid;
      memberList[off[myS[r]] + myP[r]] = i;
    }
  } else {
    int b = bid - 1;  // 0..31
    // zero 4 KB chunk of [lseRow|lseCol|Ts] = [1024, 132096), contiguous 128 KB
    if (tid < 256) {
      float4v z4 = {0.f, 0.f, 0.f, 0.f};
      *(float4v*)(ws + WS_LSEROW + b * 4096 + tid * 16) = z4;
    }
    // Tpart[b*4+q][d] = sum of tx rows [b*256+q*64, b*256+(q+1)*64) at dim d
    float* Tpart = (float*)(ws + WS_TPART);
    int d = tid & 255, q = tid >> 8;
    int row0 = b * 256 + q * 64;
    float acc = 0.f;
    #pragma unroll 8
    for (int rr = 0; rr < 64; ++rr) acc += tx[(row0 + rr) * DD + d];
    Tpart[(b * 4 + q) * DD + d] = acc;
  }
}

// ---- kB: bid<512 = k5 MFMA-LSE (R4-proven); 512..1023 = k2 Ts slices;
//          1024 = T reduce from Tpart ----
__global__ void kB(const float* __restrict__ sp, const float* __restrict__ tx,
                   const int* __restrict__ counts, const int* __restrict__ offsets,
                   const int* __restrict__ memberList, const float* __restrict__ Tpart,
                   float* Ts, float* T, float* lseRow, float* lseCol) {
  __shared__ uint4v frag[1536];  // 24 KB (k5 role)
  __shared__ int idx[192];       // tile row indices: A rows [0,64), B rows [64,192)
  int bid = blockIdx.x;
  int tid = threadIdx.x;

  if (bid == 1024) {
    // ---- T reduce: T[d] = sum_p Tpart[p][d], 128 KB L2-hot ----
    int d = tid;
    float acc = 0.f;
    #pragma unroll 8
    for (int p = 0; p < 128; ++p) acc += Tpart[p * DD + d];
    T[d] = acc;
    return;
  }
  if (bid >= 512) {
    // ---- k2 role: per-species text sums Ts[s][d], batched-gather pipeline ----
    int v2 = bid - 512;
    int s = v2 & 63, r = v2 >> 6;
    int m = counts[s], g0 = offsets[s];
    int k0 = (m * r) >> 3, k1e = (m * (r + 1)) >> 3;
    if (k0 >= k1e) return;
    int d = tid;
    float acc = 0.f;
    int k = k0;
    for (; k + 4 <= k1e; k += 4) {
      int i0 = memberList[g0 + k];
      int i1 = memberList[g0 + k + 1];
      int i2 = memberList[g0 + k + 2];
      int i3 = memberList[g0 + k + 3];
      float a0 = tx[i0 * DD + d];
      float a1 = tx[i1 * DD + d];
      float a2 = tx[i2 * DD + d];
      float a3 = tx[i3 * DD + d];
      acc += a0 + a1 + a2 + a3;
    }
    for (; k < k1e; ++k) acc += tx[memberList[g0 + k] * DD + d];
    atomicAdd(&Ts[s * DD + d], acc);
    return;
  }

  // ---- k5 role: 64x128 masked sum-of-exp via MFMA f16, K=256 in 4 chunks ----
  int s = bid & 63;
  int m = counts[s];
  int g0 = offsets[s];
  int lane = tid & 63, wv = tid >> 6;
  int quad = lane >> 4, cl = lane & 15;
  int rt0 = (bid >> 6) & 3, ct0 = (bid >> 8) & 1;  // strides 4, 2

  for (int rt = rt0; rt * 64 < m; rt += 4) {
    for (int ct = ct0; ct * 128 < m; ct += 2) {
      // tile prologue: hoist member indices to LDS ONCE per tile
      __syncthreads();
      if (tid < 192) {
        int base = (tid < 64) ? (rt * 64 + tid) : (ct * 128 + (tid - 64));
        idx[tid] = (base < m) ? memberList[g0 + base] : -1;
      }
      __syncthreads();

      const float* srcB[6];
      bool val[6];
      int dst[6];
      float4 r0[6], r1[6];
      #pragma unroll
      for (int p = 0; p < 6; ++p) {
        int u = p * 256 + tid;
        int isB = u >= 512;
        int v = isB ? (u - 512) : u;
        int row = v >> 3, sub = v & 7;
        int ksl = sub >> 2, q = sub & 3;
        int ridx = idx[isB ? (64 + row) : row];
        val[p] = ridx >= 0;
        srcB[p] = (isB ? tx : sp) + (val[p] ? ridx : 0) * DD + ksl * 32 + q * 8;
        dst[p] = isB ? (512 + (ksl * 128 + row) * 4 + q)
                     : ((ksl * 64 + row) * 4 + q);
      }
      #pragma unroll
      for (int p = 0; p < 6; ++p) {
        r0[p] = *reinterpret_cast<const float4*>(srcB[p]);
        r1[p] = *reinterpret_cast<const float4*>(srcB[p] + 4);
      }

      float4v acc[8];
      #pragma unroll
      for (int cf = 0; cf < 8; ++cf) acc[cf] = (float4v){0.f, 0.f, 0.f, 0.f};

      for (int kc = 0; kc < 4; ++kc) {
        __syncthreads();
        uint4v z4 = (uint4v){0u, 0u, 0u, 0u};
        #pragma unroll
        for (int p = 0; p < 6; ++p)
          frag[dst[p]] = val[p] ? pack8(r0[p], r1[p]) : z4;
        __syncthreads();
        if (kc < 3) {
          #pragma unroll
          for (int p = 0; p < 6; ++p) {
            r0[p] = *reinterpret_cast<const float4*>(srcB[p] + (kc + 1) * 64);
            r1[p] = *reinterpret_cast<const float4*>(srcB[p] + (kc + 1) * 64 + 4);
          }
        }
        #pragma unroll
        for (int ksl = 0; ksl < 2; ++ksl) {
          half8 a = __builtin_bit_cast(half8, frag[(ksl * 64 + wv * 16 + cl) * 4 + quad]);
          #pragma unroll
          for (int cf = 0; cf < 8; ++cf) {
            half8 b = __builtin_bit_cast(half8, frag[512 + (ksl * 128 + cf * 16 + cl) * 4 + quad]);
            acc[cf] = __builtin_amdgcn_mfma_f32_16x16x32_f16(a, b, acc[cf], 0, 0, 0);
          }
        }
      }

      // epilogue: masked exp, row/col sums
      int riBase = rt * 64 + wv * 16 + quad * 4;
      float rowAcc[4] = {0.f, 0.f, 0.f, 0.f};
      #pragma unroll
      for (int cf = 0; cf < 8; ++cf) {
        int ci = ct * 128 + cf * 16 + cl;
        bool cv = ci < m;
        float colAcc = 0.f;
        #pragma unroll
        for (int reg = 0; reg < 4; ++reg) {
          bool rv = (riBase + reg) < m;
          float e = (rv && cv) ? __expf(acc[cf][reg] * (1.f / TAU)) : 0.f;
          rowAcc[reg] += e;
          colAcc += e;
        }
        colAcc += __shfl_xor(colAcc, 16);
        colAcc += __shfl_xor(colAcc, 32);
        if (quad == 0 && cv) atomicAdd(&lseCol[g0 + ci], colAcc);
      }
      #pragma unroll
      for (int reg = 0; reg < 4; ++reg) {
        float v = rowAcc[reg];
        v += __shfl_xor(v, 1);
        v += __shfl_xor(v, 2);
        v += __shfl_xor(v, 4);
        v += __shfl_xor(v, 8);
        if (cl == 0 && (riBase + reg) < m) atomicAdd(&lseRow[g0 + riBase + reg], v);
      }
    }
  }
}

// ---- kC: fused dots + CE + triplet + done-counter finalize (verbatim, proven) ----
__global__ void kC(const float* __restrict__ sp, const float* __restrict__ tx,
                   const int* __restrict__ ids, const int* __restrict__ counts,
                   const int* __restrict__ memberList,
                   const float* __restrict__ Ts, const float* __restrict__ T,
                   const float* __restrict__ lseRow, const float* __restrict__ lseCol,
                   float* scalars, float* out) {
  __shared__ float red[32];
  int tid = threadIdx.x;
  int gt = blockIdx.x * 1024 + tid;
  int g = gt >> 6, lane = gt & 63;
  int i = memberList[g];
  int s = ids[i];
  int m = counts[s];
  float4 a = *reinterpret_cast<const float4*>(sp + i * DD + lane * 4);
  float4 b = *reinterpret_cast<const float4*>(tx + i * DD + lane * 4);
  float4 c = *reinterpret_cast<const float4*>(Ts + s * DD + lane * 4);
  float4 tv = *reinterpret_cast<const float4*>(T + lane * 4);
  float dDiag = dot4(a, b);
  float dTs   = dot4(a, c);
  float dT    = dot4(a, tv);
  #pragma unroll
  for (int o = 1; o < 64; o <<= 1) {
    dDiag += __shfl_xor(dDiag, o);
    dTs   += __shfl_xor(dTs, o);
    dT    += __shfl_xor(dT, o);
  }
  if (lane == 0) {
    float term = 0.f, tri = 0.f;
    if (m >= 2) {
      term = (__logf(lseRow[g]) + __logf(lseCol[g]) - 2.f * dDiag * (1.f / TAU)) /
             (2.f * (float)m);
      float posMean = (dTs - dDiag) / fmaxf((float)(m - 1), 1.f);
      float negMean = (dT - dTs) / fmaxf((float)(BB - m), 1.f);
      if (m <= BB - 1) tri = fmaxf(negMean - posMean + MARGIN, 0.f);
    }
    int wv = tid >> 6;
    red[wv] = term;
    red[16 + wv] = tri;
  }
  __syncthreads();
  if (tid == 0) {
    float infoS = 0.f, triS = 0.f;
    #pragma unroll
    for (int w = 0; w < 16; ++w) { infoS += red[w]; triS += red[16 + w]; }
    atomicAdd(&scalars[1], infoS);
    atomicAdd(&scalars[0], triS);
    __threadfence();
    unsigned prev = atomicAdd((unsigned*)&scalars[4], 1u);
    if (prev == (unsigned)(gridDim.x - 1)) {
      float fi = atomicAdd(&scalars[1], 0.f);
      float ft = atomicAdd(&scalars[0], 0.f);
      float nv = scalars[2];
      float nvi = scalars[3];
      out[0] = fi / fmaxf(nv, 1.f) + ft / fmaxf(nvi, 1.f);
    }
  }
}

extern "C" void kernel_launch(void* const* d_in, const int* in_sizes, int n_in,
                              void* d_out, int out_size, void* d_ws, size_t ws_size,
                              hipStream_t stream) {
  const float* sp = (const float*)d_in[0];
  const float* tx = (const float*)d_in[1];
  const int* ids = (const int*)d_in[2];
  float* out = (float*)d_out;

  char* ws = (char*)d_ws;
  float* scalars = (float*)(ws + WS_SCALARS);
  int* counts = (int*)(ws + WS_COUNTS);
  int* offsets = (int*)(ws + WS_OFFSETS);
  float* lseRow = (float*)(ws + WS_LSEROW);
  float* lseCol = (float*)(ws + WS_LSECOL);
  float* Ts = (float*)(ws + WS_TS);
  float* T = (float*)(ws + WS_T);
  int* memberList = (int*)(ws + WS_MEMBER);
  float* Tpart = (float*)(ws + WS_TPART);

  kA<<<33, 1024, 0, stream>>>(ids, tx, ws);
  kB<<<1025, 256, 0, stream>>>(sp, tx, counts, offsets, memberList, Tpart,
                               Ts, T, lseRow, lseCol);
  kC<<<512, 1024, 0, stream>>>(sp, tx, ids, counts, memberList, Ts, T,
                               lseRow, lseCol, scalars, out);
}